// Round 12
// baseline (282.279 us; speedup 1.0000x reference)
//
#include <hip/hip_runtime.h>
#include <cstdint>

typedef _Float16 h1;
typedef _Float16 h4 __attribute__((ext_vector_type(4)));
typedef _Float16 h8 __attribute__((ext_vector_type(8)));
typedef float    f4 __attribute__((ext_vector_type(4)));
typedef float    f32x4 __attribute__((ext_vector_type(4)));

#define NB 4
#define SL 4096
#define DD 512
#define MM (NB*SL)   // 16384 total rows
#define SHIFT 12.0f

// ---------------- K0: convert X(q,k,v) and W(q,k,v) f32 -> fp16 ----------------
__global__ __launch_bounds__(256) void convert_all(
    const float* __restrict__ Xq, const float* __restrict__ Xk, const float* __restrict__ Xv,
    const float* __restrict__ Wq, const float* __restrict__ Wk, const float* __restrict__ Wv,
    h1* __restrict__ Xh, h1* __restrict__ Wh)
{
    const int xper = MM*DD/4;             // f4 chunks per X matrix
    const int wper = DD*DD/4;
    const int xtot = 3*xper;
    int i = blockIdx.x * 256 + threadIdx.x;
    const float* src;
    h1* dst;
    int j;
    if (i < xtot) {
        int mat = i / xper; j = i - mat*xper;
        src = (mat==0) ? Xq : (mat==1 ? Xk : Xv);
        dst = Xh + (size_t)mat*MM*DD;
    } else {
        int t = i - xtot;
        if (t >= 3*wper) return;
        int mat = t / wper; j = t - mat*wper;
        src = (mat==0) ? Wq : (mat==1 ? Wk : Wv);
        dst = Wh + (size_t)mat*DD*DD;
    }
    f4 v = ((const f4*)src)[j];
    h4 hv;
    hv[0]=(h1)v[0]; hv[1]=(h1)v[1]; hv[2]=(h1)v[2]; hv[3]=(h1)v[3];
    ((h4*)dst)[j] = hv;
}

// ---------------- staging helpers ----------------
// 128x64 tile (16 KB), 4 waves x 4 chunks, XOR-8 chunk swizzle (gload_lds)
__device__ __forceinline__ void stage_tile(const h1* __restrict__ gbase,
                                           h1* lds, int w, int l)
{
    #pragma unroll
    for (int j = 0; j < 4; j++) {
        const int cc  = w*4 + j;
        const int row = cc*8 + (l >> 3);
        const int sc  = (l & 7) ^ (l >> 3);
        const h1* src = gbase + (size_t)row * DD + sc*8;
        void* dst = (char*)lds + cc*1024;
        __builtin_amdgcn_global_load_lds(
            (const __attribute__((address_space(1))) uint32_t*)src,
            (__attribute__((address_space(3))) uint32_t*)dst, 16, 0, 0);
    }
}

__device__ __forceinline__ h8 lds_frag(const h1* lds, int row, int lc)
{
    const int chunk = lc ^ (row & 7);
    return *(const h8*)(lds + row*64 + chunk*8);
}

// 256x32 slot (16 KB), chunk swizzle g^((row>>1)&3), 8 waves x 2 chunks
__device__ __forceinline__ void stage_slot32(const h1* __restrict__ gbase,
                                             char* ldsbase, int w, int l)
{
    #pragma unroll
    for (int j = 0; j < 2; j++) {
        const int lc  = j*512 + w*64 + l;    // linear 16B-chunk index 0..1023
        const int row = lc >> 2;
        const int ch  = lc & 3;
        const int sc  = ch ^ ((row >> 1) & 3);
        const h1* src = gbase + (size_t)row * DD + sc*8;
        __builtin_amdgcn_global_load_lds(
            (const __attribute__((address_space(1))) uint32_t*)src,
            (__attribute__((address_space(3))) uint32_t*)(ldsbase + (size_t)(j*512 + w*64)*16),
            16, 0, 0);
    }
}

__device__ __forceinline__ h8 frag32(const h1* lds, int row, int g)
{
    const int ch = g ^ ((row >> 1) & 3);
    return *(const h8*)(lds + row*32 + ch*8);
}

// ---------------- coalesced epilogues via per-wave LDS slabs ----------------
// fp16 slab: 16 rows x 72 h1 (144 B stride). Wave-private.
__device__ __forceinline__ void slab_write16(h1* slab, const float (&vals)[4][4], int g, int c)
{
    #pragma unroll
    for (int i = 0; i < 4; i++)
        #pragma unroll
        for (int nf = 0; nf < 4; nf++)
            slab[(g*4+i)*72 + nf*16 + c] = (h1)vals[i][nf];
}

__device__ __forceinline__ void slab_flush(const h1* slab, int lane, h1* gdst0, int grow)
{
    __builtin_amdgcn_wave_barrier();
    asm volatile("s_waitcnt lgkmcnt(0)" ::: "memory");
    const int rl = lane >> 3, ch = lane & 7;
    h8 v0 = *(const h8*)(slab + rl*72 + ch*8);
    h8 v1 = *(const h8*)(slab + (8+rl)*72 + ch*8);
    *(h8*)(gdst0 + (size_t)rl*grow + ch*8)     = v0;
    *(h8*)(gdst0 + (size_t)(8+rl)*grow + ch*8) = v1;
    __builtin_amdgcn_wave_barrier();
}

// f32 slab: 16 rows x 68 f32 (272 B stride; uniform banks for f4 reads).
__device__ __forceinline__ void slab_write32(float* slab, const float (&vals)[4][4], int g, int c)
{
    #pragma unroll
    for (int i = 0; i < 4; i++)
        #pragma unroll
        for (int nf = 0; nf < 4; nf++)
            slab[(g*4+i)*68 + nf*16 + c] = vals[i][nf];
}

__device__ __forceinline__ void slab_flush32(const float* slab, int lane, float* gdst0, int grow)
{
    __builtin_amdgcn_wave_barrier();
    asm volatile("s_waitcnt lgkmcnt(0)" ::: "memory");
    const int rl = lane >> 3, ch = lane & 7;
    #pragma unroll
    for (int half = 0; half < 2; half++) {
        f4 v0 = *(const f4*)(slab + rl*68     + half*32 + ch*4);
        f4 v1 = *(const f4*)(slab + (8+rl)*68 + half*32 + ch*4);
        *(f4*)(gdst0 + (size_t)rl*grow     + half*32 + ch*4) = v0;
        *(f4*)(gdst0 + (size_t)(8+rl)*grow + half*32 + ch*4) = v1;
    }
    __builtin_amdgcn_wave_barrier();
}

// ---------------- K1: X @ W^T + b for Q,K,V (pure fp16 NT GEMM) ----------------
__global__ __launch_bounds__(256) void proj_gemm(
    const h1* __restrict__ Xh, const h1* __restrict__ Wh,
    const float* __restrict__ bq, const float* __restrict__ bk, const float* __restrict__ bv,
    h1* __restrict__ Qh, h1* __restrict__ Kh, float* __restrict__ Vout)
{
    const int prj = blockIdx.z;
    const h1* __restrict__ X    = Xh + (size_t)prj * MM * DD;
    const h1* __restrict__ W    = Wh + (size_t)prj * DD * DD;
    const float* __restrict__ bias = (prj==0) ? bq : (prj==1 ? bk : bv);

    const int m0 = blockIdx.y * 128;
    const int n0 = blockIdx.x * 128;

    __shared__ h1 As[128*64];
    __shared__ h1 Bs[128*64];

    const int tid  = threadIdx.x;
    const int lane = tid & 63;
    const int wid  = tid >> 6;
    const int wm = wid >> 1, wn = wid & 1;
    const int g  = lane >> 4, c = lane & 15;

    f32x4 acc[4][4];
    #pragma unroll
    for (int i = 0; i < 4; i++)
        #pragma unroll
        for (int j = 0; j < 4; j++) acc[i][j] = (f32x4){0.f, 0.f, 0.f, 0.f};

    for (int k0 = 0; k0 < DD; k0 += 64) {
        __syncthreads();
        stage_tile(X + (size_t)m0 * DD + k0, As, wid, lane);
        stage_tile(W + (size_t)n0 * DD + k0, Bs, wid, lane);
        __syncthreads();
        #pragma unroll
        for (int kk = 0; kk < 2; kk++) {
            h8 af[4], bf[4];
            #pragma unroll
            for (int mf = 0; mf < 4; mf++) af[mf] = lds_frag(As, wm*64 + mf*16 + c, kk*4 + g);
            #pragma unroll
            for (int nf = 0; nf < 4; nf++) bf[nf] = lds_frag(Bs, wn*64 + nf*16 + c, kk*4 + g);
            #pragma unroll
            for (int mf = 0; mf < 4; mf++)
                #pragma unroll
                for (int nf = 0; nf < 4; nf++)
                    acc[mf][nf] = __builtin_amdgcn_mfma_f32_16x16x32_f16(af[mf], bf[nf], acc[mf][nf], 0, 0, 0);
        }
    }

    float bv4[4];
    #pragma unroll
    for (int nf = 0; nf < 4; nf++) bv4[nf] = bias[n0 + wn*64 + nf*16 + c];

    __syncthreads();   // all As/Bs reads done before slab reuse

    if (prj < 2) {
        h1* dstbase = (prj == 0) ? Qh : Kh;
        h1* slab = As + wid*1152;     // 16x72 h1 per wave
        #pragma unroll
        for (int mf = 0; mf < 4; mf++) {
            float vals[4][4];
            #pragma unroll
            for (int i = 0; i < 4; i++)
                #pragma unroll
                for (int nf = 0; nf < 4; nf++)
                    vals[i][nf] = acc[mf][nf][i] + bv4[nf];
            slab_write16(slab, vals, g, c);
            slab_flush(slab, lane,
                       dstbase + (size_t)(m0 + wm*64 + mf*16)*DD + n0 + wn*64, DD);
        }
    } else {
        // f32 slab: waves 0,1 in As; waves 2,3 in Bs (2 x 4352 B each)
        float* slab32 = (float*)((char*)(wid < 2 ? As : Bs) + (wid & 1)*4352);
        #pragma unroll
        for (int mf = 0; mf < 4; mf++) {
            float vals[4][4];
            #pragma unroll
            for (int i = 0; i < 4; i++)
                #pragma unroll
                for (int nf = 0; nf < 4; nf++)
                    vals[i][nf] = acc[mf][nf][i] + bv4[nf];
            slab_write32(slab32, vals, g, c);
            slab_flush32(slab32, lane,
                         Vout + (size_t)(m0 + wm*64 + mf*16)*DD + n0 + wn*64, DD);
        }
    }
}

// ---------------- K2: persistent 256x256 scores GEMM; e = exp(s/sqrt(128)-12) fp16 ----------------
// 256 blocks x 4 tiles each (same Q panel per block -> L2 reuse). Per tile:
// BK=32, 16 K-steps, 4-slot ring (128 KB LDS), depth-3 prefetch, counted vmcnt,
// 2-phase 4-barrier K-step (proven R10), slab epilogue.
__global__ __launch_bounds__(512) void scores_gemm(
    const h1* __restrict__ Qh, const h1* __restrict__ Kh,
    h1* __restrict__ Eh,
    float* __restrict__ partial)     // [MM][64]: slot = tx*4 + wn
{
    const int bid = blockIdx.x;

    __shared__ h1 Albuf[4*256*32];       // 64 KB: 4 slots x 16 KB
    __shared__ h1 Blbuf[4*256*32];       // 64 KB
    const int SLOT_H = 256*32;
    const int SLOT_B = SLOT_H*2;

    const int tid  = threadIdx.x;
    const int lane = tid & 63;
    const int wid  = tid >> 6;           // 0..7
    const int wm = wid >> 2;             // 0..1 (row half: 128 rows)
    const int wn = wid & 3;              // 0..3 (col quarter: 64 cols)
    const int g  = lane >> 4, c = lane & 15;

    #pragma unroll 1
    for (int tt = 0; tt < 4; tt++) {
        const int t_ = bid*4 + tt;           // 0..1023; same (b,ty) across tt
        const int b  = t_ >> 8;
        const int ty = (t_ >> 4) & 15;
        const int tx = t_ & 15;
        const int m0 = ty * 256;
        const int n0 = tx * 256;
        const h1* __restrict__ Qb = Qh + (size_t)b * SL * DD;
        const h1* __restrict__ Kb = Kh + (size_t)b * SL * DD;

        f32x4 acc[8][4];
        #pragma unroll
        for (int i = 0; i < 8; i++)
            #pragma unroll
            for (int j = 0; j < 4; j++) acc[i][j] = (f32x4){0.f, 0.f, 0.f, 0.f};

        __syncthreads();   // prior tile's slab reads fully retired before restaging

        // prologue: stage K-steps 0,1,2 into slots 0,1,2
        #pragma unroll
        for (int kt = 0; kt < 3; ++kt) {
            stage_slot32(Qb + (size_t)m0*DD + kt*32, (char*)Albuf + kt*SLOT_B, wid, lane);
            stage_slot32(Kb + (size_t)n0*DD + kt*32, (char*)Blbuf + kt*SLOT_B, wid, lane);
        }
        asm volatile("s_waitcnt vmcnt(8)" ::: "memory");   // slot 0 ready
        __builtin_amdgcn_s_barrier();

        for (int kt = 0; kt < 16; ++kt) {
            const int cur = kt & 3;
            const h1* Abase = Albuf + cur*SLOT_H;
            const h1* Bbase = Blbuf + cur*SLOT_H;

            // ---- phase A: af(lo) + bf reads; prefetch slot kt+3; 16 MFMA ----
            h8 af[4], bf[4];
            #pragma unroll
            for (int fm = 0; fm < 4; fm++) af[fm] = frag32(Abase, wm*128 + fm*16 + c, g);
            #pragma unroll
            for (int fn = 0; fn < 4; fn++) bf[fn] = frag32(Bbase, wn*64 + fn*16 + c, g);

            if (kt <= 12) {
                const int nk = kt + 3, ns = nk & 3;
                stage_slot32(Qb + (size_t)m0*DD + nk*32, (char*)Albuf + ns*SLOT_B, wid, lane);
                stage_slot32(Kb + (size_t)n0*DD + nk*32, (char*)Blbuf + ns*SLOT_B, wid, lane);
            }

            __builtin_amdgcn_s_barrier();
            asm volatile("s_waitcnt lgkmcnt(0)" ::: "memory");
            __builtin_amdgcn_sched_barrier(0);
            __builtin_amdgcn_s_setprio(1);
            #pragma unroll
            for (int fm = 0; fm < 4; fm++)
                #pragma unroll
                for (int fn = 0; fn < 4; fn++)
                    acc[fm][fn] = __builtin_amdgcn_mfma_f32_16x16x32_f16(af[fm], bf[fn], acc[fm][fn], 0, 0, 0);
            __builtin_amdgcn_s_setprio(0);
            __builtin_amdgcn_s_barrier();

            // ---- phase B: af(hi) reads; 16 MFMA; counted vmcnt; barrier ----
            #pragma unroll
            for (int fm = 0; fm < 4; fm++) af[fm] = frag32(Abase, wm*128 + 64 + fm*16 + c, g);

            __builtin_amdgcn_s_barrier();
            asm volatile("s_waitcnt lgkmcnt(0)" ::: "memory");
            __builtin_amdgcn_sched_barrier(0);
            __builtin_amdgcn_s_setprio(1);
            #pragma unroll
            for (int fm = 0; fm < 4; fm++)
                #pragma unroll
                for (int fn = 0; fn < 4; fn++)
                    acc[4+fm][fn] = __builtin_amdgcn_mfma_f32_16x16x32_f16(af[fm], bf[fn], acc[4+fm][fn], 0, 0, 0);
            __builtin_amdgcn_s_setprio(0);

            if (kt <= 12)      { asm volatile("s_waitcnt vmcnt(8)" ::: "memory"); }
            else if (kt == 13) { asm volatile("s_waitcnt vmcnt(4)" ::: "memory"); }
            else if (kt == 14) { asm volatile("s_waitcnt vmcnt(0)" ::: "memory"); }
            __builtin_amdgcn_s_barrier();
        }

        // epilogue: exp + rowsum partials + coalesced fp16 store via per-wave slab
        const float inv_scale = 0.08838834764831845f;   // 1/sqrt(128)
        h1* slab = Albuf + wid*1152;                    // 16x72 h1 per wave
        #pragma unroll
        for (int mf = 0; mf < 8; mf++) {
            float vals[4][4];
            #pragma unroll
            for (int i = 0; i < 4; i++) {
                const int row = m0 + wm*128 + mf*16 + g*4 + i;
                float rsum = 0.f;
                #pragma unroll
                for (int nf = 0; nf < 4; nf++) {
                    float e = __expf(fmaf(acc[mf][nf][i], inv_scale, -SHIFT));
                    vals[i][nf] = e;
                    rsum += e;
                }
                #pragma unroll
                for (int off = 1; off < 16; off <<= 1) rsum += __shfl_xor(rsum, off);
                if (c == 0)
                    partial[((size_t)b * SL + row) * 64 + tx * 4 + wn] = rsum;
            }
            slab_write16(slab, vals, g, c);
            slab_flush(slab, lane,
                       Eh + ((size_t)b * SL + m0 + wm*128 + mf*16) * SL + n0 + wn*64, SL);
        }
    }
}

// ---------------- K3: per-row  inv(sum(partial))  then  Wout = Eh * inv ----------------
__global__ __launch_bounds__(256) void rownorm(
    const float* __restrict__ partial, const h1* __restrict__ Eh,
    float* __restrict__ Wout)
{
    const int row = blockIdx.x;              // 0..MM-1
    const int tid = threadIdx.x;
    __shared__ float sinv;
    if (tid < 64) {
        float s = partial[(size_t)row * 64 + tid];
        #pragma unroll
        for (int off = 32; off > 0; off >>= 1) s += __shfl_xor(s, off);
        if (tid == 0) sinv = 1.0f / s;
    }
    __syncthreads();
    const float s = sinv;
    const h8* er = (const h8*)(Eh + (size_t)row * SL);
    f4* wr = (f4*)(Wout + (size_t)row * SL);
    #pragma unroll
    for (int jj = 0; jj < 2; jj++) {
        const int j = tid + jj*256;          // 512 h8 per row
        h8 v = er[j];
        f4 o0, o1;
        #pragma unroll
        for (int x = 0; x < 4; x++) { o0[x] = (float)v[x] * s; o1[x] = (float)v[4+x] * s; }
        wr[2*j]   = o0;
        wr[2*j+1] = o1;
    }
}

extern "C" void kernel_launch(void* const* d_in, const int* in_sizes, int n_in,
                              void* d_out, int out_size, void* d_ws, size_t ws_size,
                              hipStream_t stream)
{
    const float* q  = (const float*)d_in[0];
    const float* k  = (const float*)d_in[1];
    const float* v  = (const float*)d_in[2];
    const float* Wq = (const float*)d_in[3];
    const float* bq = (const float*)d_in[4];
    const float* Wk = (const float*)d_in[5];
    const float* bk = (const float*)d_in[6];
    const float* Wv = (const float*)d_in[7];
    const float* bv = (const float*)d_in[8];

    float* out  = (float*)d_out;
    float* Vout = out;                                 // [NB,SL,DD] f32 (output 0 == V)
    float* Wout = out + (size_t)MM * DD;               // [NB,SL,SL] weights

    char* ws = (char*)d_ws;
    h1* Xh = (h1*)ws;                                              // 48 MB
    h1* Wh = (h1*)(ws + (size_t)3*MM*DD*2);                        // 1.5 MB
    h1* Qh = (h1*)((char*)Wh + (size_t)3*DD*DD*2);                 // 16 MB
    h1* Kh = (h1*)((char*)Qh + (size_t)MM*DD*2);                   // 16 MB
    float* partial = (float*)((char*)Kh + (size_t)MM*DD*2);        // 4 MB
    float* invrow  = (float*)((char*)partial + (size_t)MM*64*4);   // 64 KB (spare)
    h1* Eh = (h1*)((char*)invrow + (size_t)MM*4);                  // 134 MB

    const int conv_chunks = (3*MM*DD + 3*DD*DD) / 4;
    convert_all<<<(conv_chunks + 255)/256, 256, 0, stream>>>(q, k, v, Wq, Wk, Wv, Xh, Wh);
    proj_gemm<<<dim3(4, 128, 3), 256, 0, stream>>>(Xh, Wh, bq, bk, bv, Qh, Kh, Vout);
    scores_gemm<<<256, 512, 0, stream>>>(Qh, Kh, Eh, partial);
    rownorm<<<MM, 256, 0, stream>>>(partial, Eh, Wout);
}

// Round 13
// 281.046 us; speedup vs baseline: 1.0044x; 1.0044x over previous
//
#include <hip/hip_runtime.h>
#include <cstdint>

typedef _Float16 h1;
typedef _Float16 h4 __attribute__((ext_vector_type(4)));
typedef _Float16 h8 __attribute__((ext_vector_type(8)));
typedef float    f4 __attribute__((ext_vector_type(4)));
typedef float    f32x4 __attribute__((ext_vector_type(4)));

#define NB 4
#define SL 4096
#define DD 512
#define MM (NB*SL)   // 16384 total rows
#define SHIFT 12.0f

// ---------------- K0: convert Wq/Wk/Wv f32 -> fp16 (1.5 MB only) ----------------
__global__ __launch_bounds__(256) void convert_w_kernel(
    const float* __restrict__ Wq, const float* __restrict__ Wk, const float* __restrict__ Wv,
    h1* __restrict__ Wh)
{
    const int per = DD*DD/4;              // 65536 f4 per matrix
    int i = blockIdx.x * 256 + threadIdx.x;
    if (i >= 3*per) return;
    int mat = i / per;
    int j = i - mat*per;
    const float* src = (mat==0) ? Wq : (mat==1 ? Wk : Wv);
    f4 v = ((const f4*)src)[j];
    h4 hv;
    hv[0]=(h1)v[0]; hv[1]=(h1)v[1]; hv[2]=(h1)v[2]; hv[3]=(h1)v[3];
    ((h4*)(Wh + (size_t)mat*DD*DD))[j] = hv;
}

// ---------------- staging helpers ----------------
// 128x64 tile (16 KB), 4 waves x 4 chunks, XOR-8 chunk swizzle (gload_lds)
__device__ __forceinline__ void stage_tile(const h1* __restrict__ gbase,
                                           h1* lds, int w, int l)
{
    #pragma unroll
    for (int j = 0; j < 4; j++) {
        const int cc  = w*4 + j;
        const int row = cc*8 + (l >> 3);
        const int sc  = (l & 7) ^ (l >> 3);
        const h1* src = gbase + (size_t)row * DD + sc*8;
        void* dst = (char*)lds + cc*1024;
        __builtin_amdgcn_global_load_lds(
            (const __attribute__((address_space(1))) uint32_t*)src,
            (__attribute__((address_space(3))) uint32_t*)dst, 16, 0, 0);
    }
}

__device__ __forceinline__ h8 lds_frag(const h1* lds, int row, int lc)
{
    const int chunk = lc ^ (row & 7);
    return *(const h8*)(lds + row*64 + chunk*8);
}

// 256x32 slot (16 KB), chunk swizzle g^((row>>1)&3), 8 waves x 2 chunks
__device__ __forceinline__ void stage_slot32(const h1* __restrict__ gbase,
                                             char* ldsbase, int w, int l)
{
    #pragma unroll
    for (int j = 0; j < 2; j++) {
        const int lc  = j*512 + w*64 + l;    // linear 16B-chunk index 0..1023
        const int row = lc >> 2;
        const int ch  = lc & 3;
        const int sc  = ch ^ ((row >> 1) & 3);
        const h1* src = gbase + (size_t)row * DD + sc*8;
        __builtin_amdgcn_global_load_lds(
            (const __attribute__((address_space(1))) uint32_t*)src,
            (__attribute__((address_space(3))) uint32_t*)(ldsbase + (size_t)(j*512 + w*64)*16),
            16, 0, 0);
    }
}

__device__ __forceinline__ h8 frag32(const h1* lds, int row, int g)
{
    const int ch = g ^ ((row >> 1) & 3);
    return *(const h8*)(lds + row*32 + ch*8);
}

// ---------------- coalesced fp16 epilogue via per-wave LDS slab ----------------
// slab: 16 rows x 72 h1 (144 B stride). Wave-private.
__device__ __forceinline__ void slab_write16(h1* slab, const float (&vals)[4][4], int g, int c)
{
    #pragma unroll
    for (int i = 0; i < 4; i++)
        #pragma unroll
        for (int nf = 0; nf < 4; nf++)
            slab[(g*4+i)*72 + nf*16 + c] = (h1)vals[i][nf];
}

__device__ __forceinline__ void slab_flush(const h1* slab, int lane, h1* gdst0, int grow)
{
    __builtin_amdgcn_wave_barrier();
    asm volatile("s_waitcnt lgkmcnt(0)" ::: "memory");
    const int rl = lane >> 3, ch = lane & 7;
    h8 v0 = *(const h8*)(slab + rl*72 + ch*8);
    h8 v1 = *(const h8*)(slab + (8+rl)*72 + ch*8);
    *(h8*)(gdst0 + (size_t)rl*grow + ch*8)     = v0;
    *(h8*)(gdst0 + (size_t)(8+rl)*grow + ch*8) = v1;
    __builtin_amdgcn_wave_barrier();
}

// ---------------- K1: X @ W^T + b for Q,K,V ----------------
// A: f32 X read directly, reg-staged + fp16 convert into padded LDS;
// B: fp16 gload_lds swizzled. Slab epilogue for Q/K; direct f32 stores for V.
__global__ __launch_bounds__(256) void proj_gemm(
    const float* __restrict__ Xq, const float* __restrict__ Xk, const float* __restrict__ Xv,
    const h1* __restrict__ Wh,
    const float* __restrict__ bq, const float* __restrict__ bk, const float* __restrict__ bv,
    h1* __restrict__ Qh, h1* __restrict__ Kh, float* __restrict__ Vout)
{
    const int prj = blockIdx.z;
    const float* __restrict__ X    = (prj==0) ? Xq : (prj==1 ? Xk : Xv);
    const h1*    __restrict__ W    = Wh + (size_t)prj * DD * DD;
    const float* __restrict__ bias = (prj==0) ? bq : (prj==1 ? bk : bv);

    const int m0 = blockIdx.y * 128;
    const int n0 = blockIdx.x * 128;

    __shared__ h1 As[128][72];   // padded: uniform-bank b128 ops
    __shared__ h1 Bs[128*64];    // linear XOR-swizzled (gload_lds)

    const int tid  = threadIdx.x;
    const int lane = tid & 63;
    const int wid  = tid >> 6;
    const int wm = wid >> 1, wn = wid & 1;      // 2x2 wave grid, each 64x64
    const int g  = lane >> 4, c = lane & 15;
    const int r  = tid >> 1,  h = tid & 1;      // staging: row, half-of-64

    f32x4 acc[4][4];
    #pragma unroll
    for (int i = 0; i < 4; i++)
        #pragma unroll
        for (int j = 0; j < 4; j++) acc[i][j] = (f32x4){0.f, 0.f, 0.f, 0.f};

    for (int k0 = 0; k0 < DD; k0 += 64) {
        __syncthreads();
        stage_tile(W + (size_t)n0 * DD + k0, Bs, wid, lane);
        // stage A: 128 rows x 64 f32 -> fp16 (each thread: 32 floats)
        {
            const f4* src = (const f4*)(X + (size_t)(m0 + r) * DD + k0 + h*32);
            f4 a0=src[0], a1=src[1], a2=src[2], a3=src[3],
               a4=src[4], a5=src[5], a6=src[6], a7=src[7];
            h8 p0, p1, p2, p3;
            #pragma unroll
            for (int j = 0; j < 4; j++) {
                p0[j]=(h1)a0[j]; p0[4+j]=(h1)a1[j];
                p1[j]=(h1)a2[j]; p1[4+j]=(h1)a3[j];
                p2[j]=(h1)a4[j]; p2[4+j]=(h1)a5[j];
                p3[j]=(h1)a6[j]; p3[4+j]=(h1)a7[j];
            }
            *(h8*)&As[r][h*32]      = p0;
            *(h8*)&As[r][h*32 + 8]  = p1;
            *(h8*)&As[r][h*32 + 16] = p2;
            *(h8*)&As[r][h*32 + 24] = p3;
        }
        __syncthreads();

        #pragma unroll
        for (int kk = 0; kk < 2; kk++) {
            h8 af[4], bf[4];
            #pragma unroll
            for (int mf = 0; mf < 4; mf++) af[mf] = *(const h8*)&As[wm*64 + mf*16 + c][kk*32 + g*8];
            #pragma unroll
            for (int nf = 0; nf < 4; nf++) bf[nf] = lds_frag(Bs, wn*64 + nf*16 + c, kk*4 + g);
            #pragma unroll
            for (int mf = 0; mf < 4; mf++)
                #pragma unroll
                for (int nf = 0; nf < 4; nf++)
                    acc[mf][nf] = __builtin_amdgcn_mfma_f32_16x16x32_f16(af[mf], bf[nf], acc[mf][nf], 0, 0, 0);
        }
    }

    float bv4[4];
    #pragma unroll
    for (int nf = 0; nf < 4; nf++) bv4[nf] = bias[n0 + wn*64 + nf*16 + c];

    __syncthreads();   // all LDS reads done before slab reuse

    if (prj < 2) {
        h1* dstbase = (prj == 0) ? Qh : Kh;
        h1* slab = &As[0][0] + wid*1152;     // 16x72 per wave
        #pragma unroll
        for (int mf = 0; mf < 4; mf++) {
            float vals[4][4];
            #pragma unroll
            for (int i = 0; i < 4; i++)
                #pragma unroll
                for (int nf = 0; nf < 4; nf++)
                    vals[i][nf] = acc[mf][nf][i] + bv4[nf];
            slab_write16(slab, vals, g, c);
            slab_flush(slab, lane,
                       dstbase + (size_t)(m0 + wm*64 + mf*16)*DD + n0 + wn*64, DD);
        }
    } else {
        #pragma unroll
        for (int mf = 0; mf < 4; mf++) {
            #pragma unroll
            for (int i = 0; i < 4; i++) {
                const int row = m0 + wm*64 + mf*16 + g*4 + i;
                #pragma unroll
                for (int nf = 0; nf < 4; nf++) {
                    const int col = n0 + wn*64 + nf*16 + c;
                    Vout[(size_t)row*DD + col] = acc[mf][nf][i] + bv4[nf];
                }
            }
        }
    }
}

// ---------------- K2: 256x256 pipelined scores GEMM (R10 verbatim) ----------------
// 512 threads = 8 waves (2M x 4N). BK=32, 16 K-steps, 4-slot ring (128 KB LDS),
// depth-3 prefetch, counted vmcnt, 2-phase K-step, slab epilogue.
__global__ __launch_bounds__(512) void scores_gemm(
    const h1* __restrict__ Qh, const h1* __restrict__ Kh,
    h1* __restrict__ Eh,
    float* __restrict__ partial)     // [MM][64]: slot = tx*4 + wn
{
    // T1 bijective XCD swizzle over 1024 blocks
    const int orig = blockIdx.x;
    const int swz  = (orig & 7) * 128 + (orig >> 3);
    const int b  = swz >> 8;             // 256 tiles per batch
    const int t_ = swz & 255;
    const int ty = t_ >> 4;
    const int tx = t_ & 15;
    const int m0 = ty * 256;
    const int n0 = tx * 256;
    const h1* __restrict__ Qb = Qh + (size_t)b * SL * DD;
    const h1* __restrict__ Kb = Kh + (size_t)b * SL * DD;

    __shared__ h1 Albuf[4*256*32];       // 64 KB: 4 slots x 16 KB
    __shared__ h1 Blbuf[4*256*32];       // 64 KB
    const int SLOT_H = 256*32;
    const int SLOT_B = SLOT_H*2;

    const int tid  = threadIdx.x;
    const int lane = tid & 63;
    const int wid  = tid >> 6;           // 0..7
    const int wm = wid >> 2;             // 0..1 (row half: 128 rows)
    const int wn = wid & 3;              // 0..3 (col quarter: 64 cols)
    const int g  = lane >> 4, c = lane & 15;

    f32x4 acc[8][4];
    #pragma unroll
    for (int i = 0; i < 8; i++)
        #pragma unroll
        for (int j = 0; j < 4; j++) acc[i][j] = (f32x4){0.f, 0.f, 0.f, 0.f};

    // prologue: stage K-steps 0,1,2 into slots 0,1,2
    #pragma unroll
    for (int kt = 0; kt < 3; ++kt) {
        stage_slot32(Qb + (size_t)m0*DD + kt*32, (char*)Albuf + kt*SLOT_B, wid, lane);
        stage_slot32(Kb + (size_t)n0*DD + kt*32, (char*)Blbuf + kt*SLOT_B, wid, lane);
    }
    asm volatile("s_waitcnt vmcnt(8)" ::: "memory");   // slot 0 ready
    __builtin_amdgcn_s_barrier();

    for (int kt = 0; kt < 16; ++kt) {
        const int cur = kt & 3;
        const h1* Abase = Albuf + cur*SLOT_H;
        const h1* Bbase = Blbuf + cur*SLOT_H;

        // ---- phase A: af(lo) + bf reads; prefetch slot kt+3; 16 MFMA ----
        h8 af[4], bf[4];
        #pragma unroll
        for (int fm = 0; fm < 4; fm++) af[fm] = frag32(Abase, wm*128 + fm*16 + c, g);
        #pragma unroll
        for (int fn = 0; fn < 4; fn++) bf[fn] = frag32(Bbase, wn*64 + fn*16 + c, g);

        if (kt <= 12) {
            const int nk = kt + 3, ns = nk & 3;
            stage_slot32(Qb + (size_t)m0*DD + nk*32, (char*)Albuf + ns*SLOT_B, wid, lane);
            stage_slot32(Kb + (size_t)n0*DD + nk*32, (char*)Blbuf + ns*SLOT_B, wid, lane);
        }

        __builtin_amdgcn_s_barrier();
        asm volatile("s_waitcnt lgkmcnt(0)" ::: "memory");
        __builtin_amdgcn_sched_barrier(0);
        __builtin_amdgcn_s_setprio(1);
        #pragma unroll
        for (int fm = 0; fm < 4; fm++)
            #pragma unroll
            for (int fn = 0; fn < 4; fn++)
                acc[fm][fn] = __builtin_amdgcn_mfma_f32_16x16x32_f16(af[fm], bf[fn], acc[fm][fn], 0, 0, 0);
        __builtin_amdgcn_s_setprio(0);
        __builtin_amdgcn_s_barrier();

        // ---- phase B: af(hi) reads; 16 MFMA; counted vmcnt; barrier ----
        #pragma unroll
        for (int fm = 0; fm < 4; fm++) af[fm] = frag32(Abase, wm*128 + 64 + fm*16 + c, g);

        __builtin_amdgcn_s_barrier();
        asm volatile("s_waitcnt lgkmcnt(0)" ::: "memory");
        __builtin_amdgcn_sched_barrier(0);
        __builtin_amdgcn_s_setprio(1);
        #pragma unroll
        for (int fm = 0; fm < 4; fm++)
            #pragma unroll
            for (int fn = 0; fn < 4; fn++)
                acc[4+fm][fn] = __builtin_amdgcn_mfma_f32_16x16x32_f16(af[fm], bf[fn], acc[4+fm][fn], 0, 0, 0);
        __builtin_amdgcn_s_setprio(0);

        if (kt <= 12)      { asm volatile("s_waitcnt vmcnt(8)" ::: "memory"); }
        else if (kt == 13) { asm volatile("s_waitcnt vmcnt(4)" ::: "memory"); }
        else if (kt == 14) { asm volatile("s_waitcnt vmcnt(0)" ::: "memory"); }
        __builtin_amdgcn_s_barrier();
    }

    // epilogue: exp + rowsum partials + coalesced fp16 store via per-wave slab
    const float inv_scale = 0.08838834764831845f;   // 1/sqrt(128)
    h1* slab = Albuf + wid*1152;                    // 16x72 per wave (2304 B)
    #pragma unroll
    for (int mf = 0; mf < 8; mf++) {
        float vals[4][4];
        #pragma unroll
        for (int i = 0; i < 4; i++) {
            const int row = m0 + wm*128 + mf*16 + g*4 + i;
            float rsum = 0.f;
            #pragma unroll
            for (int nf = 0; nf < 4; nf++) {
                float e = __expf(fmaf(acc[mf][nf][i], inv_scale, -SHIFT));
                vals[i][nf] = e;
                rsum += e;
            }
            #pragma unroll
            for (int off = 1; off < 16; off <<= 1) rsum += __shfl_xor(rsum, off);
            if (c == 0)
                partial[((size_t)b * SL + row) * 64 + tx * 4 + wn] = rsum;
        }
        slab_write16(slab, vals, g, c);
        slab_flush(slab, lane,
                   Eh + ((size_t)b * SL + m0 + wm*128 + mf*16) * SL + n0 + wn*64, SL);
    }
}

// ---------------- K3: per-row  inv(sum(partial))  then  Wout = Eh * inv ----------------
__global__ __launch_bounds__(256) void rownorm(
    const float* __restrict__ partial, const h1* __restrict__ Eh,
    float* __restrict__ Wout)
{
    const int row = blockIdx.x;              // 0..MM-1
    const int tid = threadIdx.x;
    __shared__ float sinv;
    if (tid < 64) {
        float s = partial[(size_t)row * 64 + tid];
        #pragma unroll
        for (int off = 32; off > 0; off >>= 1) s += __shfl_xor(s, off);
        if (tid == 0) sinv = 1.0f / s;
    }
    __syncthreads();
    const float s = sinv;
    const h8* er = (const h8*)(Eh + (size_t)row * SL);
    f4* wr = (f4*)(Wout + (size_t)row * SL);
    #pragma unroll
    for (int jj = 0; jj < 2; jj++) {
        const int j = tid + jj*256;          // 512 h8 per row
        h8 v = er[j];
        f4 o0, o1;
        #pragma unroll
        for (int x = 0; x < 4; x++) { o0[x] = (float)v[x] * s; o1[x] = (float)v[4+x] * s; }
        wr[2*j]   = o0;
        wr[2*j+1] = o1;
    }
}

extern "C" void kernel_launch(void* const* d_in, const int* in_sizes, int n_in,
                              void* d_out, int out_size, void* d_ws, size_t ws_size,
                              hipStream_t stream)
{
    const float* q  = (const float*)d_in[0];
    const float* k  = (const float*)d_in[1];
    const float* v  = (const float*)d_in[2];
    const float* Wq = (const float*)d_in[3];
    const float* bq = (const float*)d_in[4];
    const float* Wk = (const float*)d_in[5];
    const float* bk = (const float*)d_in[6];
    const float* Wv = (const float*)d_in[7];
    const float* bv = (const float*)d_in[8];

    float* out  = (float*)d_out;
    float* Vout = out;                                 // [NB,SL,DD] f32 (output 0 == V)
    float* Wout = out + (size_t)MM * DD;               // [NB,SL,SL] weights

    char* ws = (char*)d_ws;
    h1* Wh = (h1*)ws;                                              // 1.5 MB
    h1* Qh = (h1*)(ws + (size_t)3*DD*DD*2);                        // 16 MB
    h1* Kh = (h1*)((char*)Qh + (size_t)MM*DD*2);                   // 16 MB
    float* partial = (float*)((char*)Kh + (size_t)MM*DD*2);        // 4 MB
    float* invrow  = (float*)((char*)partial + (size_t)MM*64*4);   // 64 KB (spare)
    h1* Eh = (h1*)((char*)invrow + (size_t)MM*4);                  // 134 MB

    convert_w_kernel<<<768, 256, 0, stream>>>(Wq, Wk, Wv, Wh);
    proj_gemm<<<dim3(4, 128, 3), 256, 0, stream>>>(q, k, v, Wh, bq, bk, bv, Qh, Kh, Vout);
    scores_gemm<<<1024, 512, 0, stream>>>(Qh, Kh, Eh, partial);
    rownorm<<<MM, 256, 0, stream>>>(partial, Eh, Wout);
}

// Round 14
// 264.870 us; speedup vs baseline: 1.0657x; 1.0611x over previous
//
#include <hip/hip_runtime.h>
#include <cstdint>

typedef _Float16 h1;
typedef _Float16 h4 __attribute__((ext_vector_type(4)));
typedef _Float16 h8 __attribute__((ext_vector_type(8)));
typedef float    f4 __attribute__((ext_vector_type(4)));
typedef float    f32x4 __attribute__((ext_vector_type(4)));

#define NB 4
#define SL 4096
#define DD 512
#define MM (NB*SL)   // 16384 total rows
#define SHIFT 12.0f

// ---------------- K0: convert X(q,k,v) and W(q,k,v) f32 -> fp16 ----------------
__global__ __launch_bounds__(256) void convert_all(
    const float* __restrict__ Xq, const float* __restrict__ Xk, const float* __restrict__ Xv,
    const float* __restrict__ Wq, const float* __restrict__ Wk, const float* __restrict__ Wv,
    h1* __restrict__ Xh, h1* __restrict__ Wh)
{
    const int xper = MM*DD/4;             // f4 chunks per X matrix
    const int wper = DD*DD/4;
    const int xtot = 3*xper;
    int i = blockIdx.x * 256 + threadIdx.x;
    const float* src;
    h1* dst;
    int j;
    if (i < xtot) {
        int mat = i / xper; j = i - mat*xper;
        src = (mat==0) ? Xq : (mat==1 ? Xk : Xv);
        dst = Xh + (size_t)mat*MM*DD;
    } else {
        int t = i - xtot;
        if (t >= 3*wper) return;
        int mat = t / wper; j = t - mat*wper;
        src = (mat==0) ? Wq : (mat==1 ? Wk : Wv);
        dst = Wh + (size_t)mat*DD*DD;
    }
    f4 v = ((const f4*)src)[j];
    h4 hv;
    hv[0]=(h1)v[0]; hv[1]=(h1)v[1]; hv[2]=(h1)v[2]; hv[3]=(h1)v[3];
    ((h4*)dst)[j] = hv;
}

// ---------------- staging helpers ----------------
// 128x64 tile (16 KB), 4 waves x 4 chunks, XOR-8 chunk swizzle (gload_lds)
__device__ __forceinline__ void stage_tile(const h1* __restrict__ gbase,
                                           h1* lds, int w, int l)
{
    #pragma unroll
    for (int j = 0; j < 4; j++) {
        const int cc  = w*4 + j;
        const int row = cc*8 + (l >> 3);
        const int sc  = (l & 7) ^ (l >> 3);
        const h1* src = gbase + (size_t)row * DD + sc*8;
        void* dst = (char*)lds + cc*1024;
        __builtin_amdgcn_global_load_lds(
            (const __attribute__((address_space(1))) uint32_t*)src,
            (__attribute__((address_space(3))) uint32_t*)dst, 16, 0, 0);
    }
}

__device__ __forceinline__ h8 lds_frag(const h1* lds, int row, int lc)
{
    const int chunk = lc ^ (row & 7);
    return *(const h8*)(lds + row*64 + chunk*8);
}

// 256x32 slot (16 KB), chunk swizzle g^((row>>1)&3), 8 waves x 2 chunks
__device__ __forceinline__ void stage_slot32(const h1* __restrict__ gbase,
                                             char* ldsbase, int w, int l)
{
    #pragma unroll
    for (int j = 0; j < 2; j++) {
        const int lc  = j*512 + w*64 + l;    // linear 16B-chunk index 0..1023
        const int row = lc >> 2;
        const int ch  = lc & 3;
        const int sc  = ch ^ ((row >> 1) & 3);
        const h1* src = gbase + (size_t)row * DD + sc*8;
        __builtin_amdgcn_global_load_lds(
            (const __attribute__((address_space(1))) uint32_t*)src,
            (__attribute__((address_space(3))) uint32_t*)(ldsbase + (size_t)(j*512 + w*64)*16),
            16, 0, 0);
    }
}

__device__ __forceinline__ h8 frag32(const h1* lds, int row, int g)
{
    const int ch = g ^ ((row >> 1) & 3);
    return *(const h8*)(lds + row*32 + ch*8);
}

// ---------------- coalesced fp16 epilogue via per-wave LDS slab ----------------
// slab: 16 rows x 72 h1 (144 B stride). Wave-private.
__device__ __forceinline__ void slab_write16(h1* slab, const float (&vals)[4][4], int g, int c)
{
    #pragma unroll
    for (int i = 0; i < 4; i++)
        #pragma unroll
        for (int nf = 0; nf < 4; nf++)
            slab[(g*4+i)*72 + nf*16 + c] = (h1)vals[i][nf];
}

__device__ __forceinline__ void slab_flush(const h1* slab, int lane, h1* gdst0, int grow)
{
    __builtin_amdgcn_wave_barrier();
    asm volatile("s_waitcnt lgkmcnt(0)" ::: "memory");
    const int rl = lane >> 3, ch = lane & 7;
    h8 v0 = *(const h8*)(slab + rl*72 + ch*8);
    h8 v1 = *(const h8*)(slab + (8+rl)*72 + ch*8);
    *(h8*)(gdst0 + (size_t)rl*grow + ch*8)     = v0;
    *(h8*)(gdst0 + (size_t)(8+rl)*grow + ch*8) = v1;
    __builtin_amdgcn_wave_barrier();
}

// ---------------- K1: X @ W^T + b for Q,K,V (pure fp16 NT GEMM) ----------------
__global__ __launch_bounds__(256) void proj_gemm(
    const h1* __restrict__ Xh, const h1* __restrict__ Wh,
    const float* __restrict__ bq, const float* __restrict__ bk, const float* __restrict__ bv,
    h1* __restrict__ Qh, h1* __restrict__ Kh, float* __restrict__ Vout)
{
    const int prj = blockIdx.z;
    const h1* __restrict__ X    = Xh + (size_t)prj * MM * DD;
    const h1* __restrict__ W    = Wh + (size_t)prj * DD * DD;
    const float* __restrict__ bias = (prj==0) ? bq : (prj==1 ? bk : bv);

    const int m0 = blockIdx.y * 128;
    const int n0 = blockIdx.x * 128;

    __shared__ h1 As[128*64];
    __shared__ h1 Bs[128*64];

    const int tid  = threadIdx.x;
    const int lane = tid & 63;
    const int wid  = tid >> 6;
    const int wm = wid >> 1, wn = wid & 1;
    const int g  = lane >> 4, c = lane & 15;

    f32x4 acc[4][4];
    #pragma unroll
    for (int i = 0; i < 4; i++)
        #pragma unroll
        for (int j = 0; j < 4; j++) acc[i][j] = (f32x4){0.f, 0.f, 0.f, 0.f};

    for (int k0 = 0; k0 < DD; k0 += 64) {
        __syncthreads();
        stage_tile(X + (size_t)m0 * DD + k0, As, wid, lane);
        stage_tile(W + (size_t)n0 * DD + k0, Bs, wid, lane);
        __syncthreads();
        #pragma unroll
        for (int kk = 0; kk < 2; kk++) {
            h8 af[4], bf[4];
            #pragma unroll
            for (int mf = 0; mf < 4; mf++) af[mf] = lds_frag(As, wm*64 + mf*16 + c, kk*4 + g);
            #pragma unroll
            for (int nf = 0; nf < 4; nf++) bf[nf] = lds_frag(Bs, wn*64 + nf*16 + c, kk*4 + g);
            #pragma unroll
            for (int mf = 0; mf < 4; mf++)
                #pragma unroll
                for (int nf = 0; nf < 4; nf++)
                    acc[mf][nf] = __builtin_amdgcn_mfma_f32_16x16x32_f16(af[mf], bf[nf], acc[mf][nf], 0, 0, 0);
        }
    }

    float bv4[4];
    #pragma unroll
    for (int nf = 0; nf < 4; nf++) bv4[nf] = bias[n0 + wn*64 + nf*16 + c];

    __syncthreads();   // all As/Bs reads done before slab reuse

    if (prj < 2) {
        h1* dstbase = (prj == 0) ? Qh : Kh;
        h1* slab = As + wid*1152;     // 16x72 per wave
        #pragma unroll
        for (int mf = 0; mf < 4; mf++) {
            float vals[4][4];
            #pragma unroll
            for (int i = 0; i < 4; i++)
                #pragma unroll
                for (int nf = 0; nf < 4; nf++)
                    vals[i][nf] = acc[mf][nf][i] + bv4[nf];
            slab_write16(slab, vals, g, c);
            slab_flush(slab, lane,
                       dstbase + (size_t)(m0 + wm*64 + mf*16)*DD + n0 + wn*64, DD);
        }
    } else {
        #pragma unroll
        for (int mf = 0; mf < 4; mf++) {
            #pragma unroll
            for (int i = 0; i < 4; i++) {
                const int row = m0 + wm*64 + mf*16 + g*4 + i;
                #pragma unroll
                for (int nf = 0; nf < 4; nf++) {
                    const int col = n0 + wn*64 + nf*16 + c;
                    Vout[(size_t)row*DD + col] = acc[mf][nf][i] + bv4[nf];
                }
            }
        }
    }
}

// ---------------- K2: 256x256 pipelined scores GEMM; e = exp(s/sqrt(128)-12) fp16 ----------------
// 512 threads = 8 waves (2M x 4N). BK=32, 16 K-steps, 4-slot ring (128 KB LDS),
// depth-3 prefetch, counted vmcnt. Epilogue through per-wave LDS slab (coalesced h8 stores).
__global__ __launch_bounds__(512) void scores_gemm_8ph(
    const h1* __restrict__ Qh, const h1* __restrict__ Kh,
    h1* __restrict__ Eh,
    float* __restrict__ partial)     // [MM][64]: slot = tx*4 + wn
{
    // T1 bijective XCD swizzle over 1024 blocks
    const int orig = blockIdx.x;
    const int swz  = (orig & 7) * 128 + (orig >> 3);
    const int b  = swz >> 8;             // 256 tiles per batch
    const int t_ = swz & 255;
    const int ty = t_ >> 4;
    const int tx = t_ & 15;
    const int m0 = ty * 256;
    const int n0 = tx * 256;
    const h1* __restrict__ Qb = Qh + (size_t)b * SL * DD;
    const h1* __restrict__ Kb = Kh + (size_t)b * SL * DD;

    __shared__ h1 Albuf[4*256*32];       // 64 KB: 4 slots x 16 KB
    __shared__ h1 Blbuf[4*256*32];       // 64 KB
    const int SLOT_H = 256*32;
    const int SLOT_B = SLOT_H*2;

    const int tid  = threadIdx.x;
    const int lane = tid & 63;
    const int wid  = tid >> 6;           // 0..7
    const int wm = wid >> 2;             // 0..1 (row half: 128 rows)
    const int wn = wid & 3;              // 0..3 (col quarter: 64 cols)
    const int g  = lane >> 4, c = lane & 15;

    f32x4 acc[8][4];
    #pragma unroll
    for (int i = 0; i < 8; i++)
        #pragma unroll
        for (int j = 0; j < 4; j++) acc[i][j] = (f32x4){0.f, 0.f, 0.f, 0.f};

    // prologue: stage K-steps 0,1,2 into slots 0,1,2
    #pragma unroll
    for (int kt = 0; kt < 3; ++kt) {
        stage_slot32(Qb + (size_t)m0*DD + kt*32, (char*)Albuf + kt*SLOT_B, wid, lane);
        stage_slot32(Kb + (size_t)n0*DD + kt*32, (char*)Blbuf + kt*SLOT_B, wid, lane);
    }
    asm volatile("s_waitcnt vmcnt(8)" ::: "memory");   // slot 0 ready
    __builtin_amdgcn_s_barrier();

    for (int kt = 0; kt < 16; ++kt) {
        const int cur = kt & 3;
        const h1* Abase = Albuf + cur*SLOT_H;
        const h1* Bbase = Blbuf + cur*SLOT_H;

        // ---- phase A: af(lo) + bf reads; prefetch slot kt+3; 16 MFMA ----
        h8 af[4], bf[4];
        #pragma unroll
        for (int fm = 0; fm < 4; fm++) af[fm] = frag32(Abase, wm*128 + fm*16 + c, g);
        #pragma unroll
        for (int fn = 0; fn < 4; fn++) bf[fn] = frag32(Bbase, wn*64 + fn*16 + c, g);

        if (kt <= 12) {
            const int nk = kt + 3, ns = nk & 3;
            stage_slot32(Qb + (size_t)m0*DD + nk*32, (char*)Albuf + ns*SLOT_B, wid, lane);
            stage_slot32(Kb + (size_t)n0*DD + nk*32, (char*)Blbuf + ns*SLOT_B, wid, lane);
        }

        __builtin_amdgcn_s_barrier();
        asm volatile("s_waitcnt lgkmcnt(0)" ::: "memory");
        __builtin_amdgcn_sched_barrier(0);
        __builtin_amdgcn_s_setprio(1);
        #pragma unroll
        for (int fm = 0; fm < 4; fm++)
            #pragma unroll
            for (int fn = 0; fn < 4; fn++)
                acc[fm][fn] = __builtin_amdgcn_mfma_f32_16x16x32_f16(af[fm], bf[fn], acc[fm][fn], 0, 0, 0);
        __builtin_amdgcn_s_setprio(0);
        __builtin_amdgcn_s_barrier();

        // ---- phase B: af(hi) reads; 16 MFMA; counted vmcnt; barrier ----
        #pragma unroll
        for (int fm = 0; fm < 4; fm++) af[fm] = frag32(Abase, wm*128 + 64 + fm*16 + c, g);

        __builtin_amdgcn_s_barrier();
        asm volatile("s_waitcnt lgkmcnt(0)" ::: "memory");
        __builtin_amdgcn_sched_barrier(0);
        __builtin_amdgcn_s_setprio(1);
        #pragma unroll
        for (int fm = 0; fm < 4; fm++)
            #pragma unroll
            for (int fn = 0; fn < 4; fn++)
                acc[4+fm][fn] = __builtin_amdgcn_mfma_f32_16x16x32_f16(af[fm], bf[fn], acc[4+fm][fn], 0, 0, 0);
        __builtin_amdgcn_s_setprio(0);

        if (kt <= 12)      { asm volatile("s_waitcnt vmcnt(8)" ::: "memory"); }
        else if (kt == 13) { asm volatile("s_waitcnt vmcnt(4)" ::: "memory"); }
        else if (kt == 14) { asm volatile("s_waitcnt vmcnt(0)" ::: "memory"); }
        __builtin_amdgcn_s_barrier();
    }

    // epilogue: exp + rowsum partials + coalesced fp16 store via per-wave slab
    const float inv_scale = 0.08838834764831845f;   // 1/sqrt(128)
    h1* slab = Albuf + wid*1152;                    // 16x72 per wave (2304 B)
    #pragma unroll
    for (int mf = 0; mf < 8; mf++) {
        float vals[4][4];
        #pragma unroll
        for (int i = 0; i < 4; i++) {
            const int row = m0 + wm*128 + mf*16 + g*4 + i;
            float rsum = 0.f;
            #pragma unroll
            for (int nf = 0; nf < 4; nf++) {
                float e = __expf(fmaf(acc[mf][nf][i], inv_scale, -SHIFT));
                vals[i][nf] = e;
                rsum += e;
            }
            #pragma unroll
            for (int off = 1; off < 16; off <<= 1) rsum += __shfl_xor(rsum, off);
            if (c == 0)
                partial[((size_t)b * SL + row) * 64 + tx * 4 + wn] = rsum;
        }
        slab_write16(slab, vals, g, c);
        slab_flush(slab, lane,
                   Eh + ((size_t)b * SL + m0 + wm*128 + mf*16) * SL + n0 + wn*64, SL);
    }
}

// ---------------- K3: per-row  inv(sum(partial))  then  Wout = Eh * inv ----------------
__global__ __launch_bounds__(256) void rownorm(
    const float* __restrict__ partial, const h1* __restrict__ Eh,
    float* __restrict__ Wout)
{
    const int row = blockIdx.x;              // 0..MM-1
    const int tid = threadIdx.x;
    __shared__ float sinv;
    if (tid < 64) {
        float s = partial[(size_t)row * 64 + tid];
        #pragma unroll
        for (int off = 32; off > 0; off >>= 1) s += __shfl_xor(s, off);
        if (tid == 0) sinv = 1.0f / s;
    }
    __syncthreads();
    const float s = sinv;
    const h8* er = (const h8*)(Eh + (size_t)row * SL);
    f4* wr = (f4*)(Wout + (size_t)row * SL);
    #pragma unroll
    for (int jj = 0; jj < 2; jj++) {
        const int j = tid + jj*256;          // 512 h8 per row
        h8 v = er[j];
        f4 o0, o1;
        #pragma unroll
        for (int x = 0; x < 4; x++) { o0[x] = (float)v[x] * s; o1[x] = (float)v[4+x] * s; }
        wr[2*j]   = o0;
        wr[2*j+1] = o1;
    }
}

extern "C" void kernel_launch(void* const* d_in, const int* in_sizes, int n_in,
                              void* d_out, int out_size, void* d_ws, size_t ws_size,
                              hipStream_t stream)
{
    const float* q  = (const float*)d_in[0];
    const float* k  = (const float*)d_in[1];
    const float* v  = (const float*)d_in[2];
    const float* Wq = (const float*)d_in[3];
    const float* bq = (const float*)d_in[4];
    const float* Wk = (const float*)d_in[5];
    const float* bk = (const float*)d_in[6];
    const float* Wv = (const float*)d_in[7];
    const float* bv = (const float*)d_in[8];

    float* out  = (float*)d_out;
    float* Vout = out;                                 // [NB,SL,DD] f32 (output 0 == V)
    float* Wout = out + (size_t)MM * DD;               // [NB,SL,SL] weights

    char* ws = (char*)d_ws;
    h1* Xh = (h1*)ws;                                              // 48 MB
    h1* Wh = (h1*)(ws + (size_t)3*MM*DD*2);                        // 1.5 MB
    h1* Qh = (h1*)((char*)Wh + (size_t)3*DD*DD*2);                 // 16 MB
    h1* Kh = (h1*)((char*)Qh + (size_t)MM*DD*2);                   // 16 MB
    float* partial = (float*)((char*)Kh + (size_t)MM*DD*2);        // 4 MB
    float* invrow  = (float*)((char*)partial + (size_t)MM*64*4);   // 64 KB (spare)
    h1* Eh = (h1*)((char*)invrow + (size_t)MM*4);                  // 134 MB

    const int conv_chunks = (3*MM*DD + 3*DD*DD) / 4;
    convert_all<<<(conv_chunks + 255)/256, 256, 0, stream>>>(q, k, v, Wq, Wk, Wv, Xh, Wh);
    proj_gemm<<<dim3(4, 128, 3), 256, 0, stream>>>(Xh, Wh, bq, bk, bv, Qh, Kh, Vout);
    scores_gemm_8ph<<<1024, 512, 0, stream>>>(Qh, Kh, Eh, partial);
    rownorm<<<MM, 256, 0, stream>>>(partial, Eh, Wout);
}